// Round 1
// baseline (178.373 us; speedup 1.0000x reference)
//
#include <hip/hip_runtime.h>
#include <hip/hip_bf16.h>
#include <stdint.h>

#define B_ 4
#define S_ 1024
#define D_ 1024
#define E_ 8
#define DE_ 128
#define SCALE_ 0.03125f   // 1/sqrt(1024)

typedef __attribute__((ext_vector_type(8))) short short8;
typedef __attribute__((ext_vector_type(4))) float f32x4;
typedef unsigned short ushort_t;
typedef unsigned int uint32;

__device__ __forceinline__ ushort_t f2bf(float f) {
    uint32 u = __float_as_uint(f);
    uint32 r = u + 0x7fffu + ((u >> 16) & 1u);   // round-to-nearest-even
    return (ushort_t)(r >> 16);
}
__device__ __forceinline__ float bf2f(ushort_t h) {
    return __uint_as_float(((uint32)h) << 16);
}

// ---------------------------------------------------------------------------
// Kernel 1: convert Q,K,V fp32 [B][S][E*DE] -> bf16 [B][E][S][DE]
// ---------------------------------------------------------------------------
__global__ __launch_bounds__(256) void prep_kernel(
        const float* __restrict__ Q, const float* __restrict__ K,
        const float* __restrict__ V,
        ushort_t* __restrict__ Qb, ushort_t* __restrict__ Kb,
        ushort_t* __restrict__ Vb) {
    int i = blockIdx.x * 256 + threadIdx.x;          // 0 .. 1M-1 (elements/4)
    int dc = i & 31;                                  // DE/4 chunks
    int e  = (i >> 5) & 7;
    int s  = (i >> 8) & 1023;
    int b  = i >> 18;
    size_t in_off  = ((size_t)(b * 1024 + s) << 10) + ((size_t)e << 7) + ((size_t)dc << 2);
    size_t out_off = (((size_t)(b * 8 + e) * 1024 + s) << 7) + ((size_t)dc << 2);

    float4 q = *(const float4*)(Q + in_off);
    float4 k = *(const float4*)(K + in_off);
    float4 v = *(const float4*)(V + in_off);
    *(ushort4*)(Qb + out_off) = make_ushort4(f2bf(q.x), f2bf(q.y), f2bf(q.z), f2bf(q.w));
    *(ushort4*)(Kb + out_off) = make_ushort4(f2bf(k.x), f2bf(k.y), f2bf(k.z), f2bf(k.w));
    *(ushort4*)(Vb + out_off) = make_ushort4(f2bf(v.x), f2bf(v.y), f2bf(v.z), f2bf(v.w));
}

// ---------------------------------------------------------------------------
// Kernel 2: attn[b][s][t] = sum_e mask[e][b] * softmax_t( (Qe.Ke^T)[s][t] / 32 )
// Block = (s-tile of 16 rows, b). 4 waves; wave w owns t in [w*256, w*256+256).
// ---------------------------------------------------------------------------
__global__ __launch_bounds__(256, 1) void attn_pass1(
        const ushort_t* __restrict__ Qb, const ushort_t* __restrict__ Kb,
        const int* __restrict__ em, float* __restrict__ attnW) {

    __shared__ ushort_t qtile[16][136];        // +8 pad: 272B pitch -> 2-way free
    __shared__ ushort_t ktile[4][64][136];
    __shared__ float    redbuf[4][16];

    const int tid  = threadIdx.x;
    const int w    = tid >> 6, lane = tid & 63;
    const int quad = lane >> 4, l16 = lane & 15;
    const int stile = blockIdx.x, b = blockIdx.y;
    const int s0 = stile * 16;

    const f32x4 zero4 = {0.f, 0.f, 0.f, 0.f};
    f32x4 aacc[16];
    #pragma unroll
    for (int i = 0; i < 16; ++i) aacc[i] = zero4;

    for (int e = 0; e < 8; ++e) {
        if (em[e * B_ + b] == 0) continue;     // uniform per block

        const ushort_t* qsrc  = Qb + (((size_t)(b * 8 + e) << 10) + s0) * 128;
        const ushort_t* ksrc0 = Kb + (((size_t)(b * 8 + e) << 10)) * 128;

        f32x4 sacc[16];
        #pragma unroll
        for (int i = 0; i < 16; ++i) sacc[i] = zero4;

        for (int c = 0; c < 4; ++c) {
            __syncthreads();                    // previous chunk reads done
            if (c == 0) {                       // stage Q tile: 16x128
                int r = tid >> 4, cc = (tid & 15) << 3;
                *(uint4*)&qtile[r][cc] = *(const uint4*)&qsrc[(r << 7) + cc];
            }
            {                                   // stage K chunk for this wave
                const ushort_t* ksrc = ksrc0 + (size_t)(w * 256 + c * 64) * 128;
                #pragma unroll
                for (int i2 = 0; i2 < 16; ++i2) {
                    int i = lane + i2 * 64;
                    int r = i >> 4, cc = (i & 15) << 3;
                    *(uint4*)&ktile[w][r][cc] = *(const uint4*)&ksrc[(r << 7) + cc];
                }
            }
            __syncthreads();
            #pragma unroll
            for (int kk = 0; kk < 128; kk += 32) {
                short8 afrag = *(const short8*)&qtile[l16][kk + quad * 8];
                #pragma unroll
                for (int n = 0; n < 4; ++n) {
                    short8 bfrag = *(const short8*)&ktile[w][n * 16 + l16][kk + quad * 8];
                    sacc[c * 4 + n] = __builtin_amdgcn_mfma_f32_16x16x32_bf16(
                        afrag, bfrag, sacc[c * 4 + n], 0, 0, 0);
                }
            }
        }

        // ---- softmax over t (rows s = quad*4 + r) ----
        float rmax[4] = {-1e30f, -1e30f, -1e30f, -1e30f};
        #pragma unroll
        for (int i = 0; i < 16; ++i)
            #pragma unroll
            for (int r = 0; r < 4; ++r) rmax[r] = fmaxf(rmax[r], sacc[i][r]);
        #pragma unroll
        for (int off = 1; off < 16; off <<= 1)
            #pragma unroll
            for (int r = 0; r < 4; ++r)
                rmax[r] = fmaxf(rmax[r], __shfl_xor(rmax[r], off, 64));
        if (l16 == 0) {
            #pragma unroll
            for (int r = 0; r < 4; ++r) redbuf[w][quad * 4 + r] = rmax[r];
        }
        __syncthreads();
        #pragma unroll
        for (int r = 0; r < 4; ++r) {
            float m = fmaxf(fmaxf(redbuf[0][quad * 4 + r], redbuf[1][quad * 4 + r]),
                            fmaxf(redbuf[2][quad * 4 + r], redbuf[3][quad * 4 + r]));
            rmax[r] = m;
        }
        __syncthreads();                        // redbuf reused for sums

        float rsum[4] = {0.f, 0.f, 0.f, 0.f};
        #pragma unroll
        for (int i = 0; i < 16; ++i)
            #pragma unroll
            for (int r = 0; r < 4; ++r) {
                float p = __expf((sacc[i][r] - rmax[r]) * SCALE_);
                sacc[i][r] = p;
                rsum[r] += p;
            }
        #pragma unroll
        for (int off = 1; off < 16; off <<= 1)
            #pragma unroll
            for (int r = 0; r < 4; ++r) rsum[r] += __shfl_xor(rsum[r], off, 64);
        if (l16 == 0) {
            #pragma unroll
            for (int r = 0; r < 4; ++r) redbuf[w][quad * 4 + r] = rsum[r];
        }
        __syncthreads();
        #pragma unroll
        for (int r = 0; r < 4; ++r) {
            float l = redbuf[0][quad * 4 + r] + redbuf[1][quad * 4 + r] +
                      redbuf[2][quad * 4 + r] + redbuf[3][quad * 4 + r];
            float rinv = 1.0f / l;              // l >= 1 always (max term = 1)
            #pragma unroll
            for (int i = 0; i < 16; ++i) aacc[i][r] += sacc[i][r] * rinv;
        }
    }

    // ---- write attn tile ----
    float* arow = attnW + ((size_t)(b * 1024 + s0)) * 1024;
    #pragma unroll
    for (int i = 0; i < 16; ++i) {
        int t0 = w * 256 + ((i >> 2) * 64) + ((i & 3) * 16) + l16;
        #pragma unroll
        for (int r = 0; r < 4; ++r)
            arow[(size_t)(quad * 4 + r) * 1024 + t0] = aacc[i][r];
    }
}

// ---------------------------------------------------------------------------
// Kernel 3: out[b][s][e*128+d] = (attn @ V_e) if e in top2(route_prob[b]) else 0
// Block = (s-tile 16, e, b). attn staged as bf16 hi+lo for accuracy.
// ---------------------------------------------------------------------------
__global__ __launch_bounds__(256, 1) void attn_pass2(
        const ushort_t* __restrict__ Vb, const float* __restrict__ attnW,
        const float* __restrict__ route, float* __restrict__ out) {

    const int stile = blockIdx.x;      // 0..63
    const int e     = blockIdx.y;      // 0..7
    const int b     = blockIdx.z;      // 0..3
    const int s0  = stile * 16;
    const int tid = threadIdx.x;
    const int w = tid >> 6, lane = tid & 63, quad = lane >> 4, l16 = lane & 15;

    // top-2 selection (uniform per block; ties -> lower index, matches lax.top_k)
    const float* rp = route + b * 8;
    float v1 = rp[0]; int i1 = 0;
    #pragma unroll
    for (int i = 1; i < 8; ++i) { float v = rp[i]; if (v > v1) { v1 = v; i1 = i; } }
    float v2 = -1e30f; int i2 = -1;
    #pragma unroll
    for (int i = 0; i < 8; ++i) {
        if (i == i1) continue;
        float v = rp[i]; if (v > v2) { v2 = v; i2 = i; }
    }
    bool sel = (e == i1) || (e == i2);

    float* obase = out + ((size_t)(b * 1024 + s0)) * 1024 + e * 128;

    if (!sel) {
        #pragma unroll
        for (int i = 0; i < 2; ++i) {
            int idx = tid + i * 256;            // 512 float4s
            int r = idx >> 5, cc = (idx & 31) << 2;
            *(float4*)&obase[(size_t)r * 1024 + cc] = make_float4(0.f, 0.f, 0.f, 0.f);
        }
        return;
    }

    __shared__ ushort_t ahi[16][72];
    __shared__ ushort_t alo[16][72];
    __shared__ ushort_t vt[128][72];            // V transposed: [d][t]

    const float* arow = attnW + ((size_t)(b * 1024 + s0)) * 1024;
    const ushort_t* vsrc0 = Vb + (((size_t)(b * 8 + e) << 10)) * 128;

    f32x4 oacc[2];
    oacc[0] = (f32x4){0.f, 0.f, 0.f, 0.f};
    oacc[1] = (f32x4){0.f, 0.f, 0.f, 0.f};

    for (int tc = 0; tc < 16; ++tc) {
        __syncthreads();
        {   // stage attn 16 x 64 -> hi/lo bf16
            int r = tid >> 4, j = (tid & 15) << 2;
            float4 v = *(const float4*)&arow[(size_t)r * 1024 + tc * 64 + j];
            float vv[4] = {v.x, v.y, v.z, v.w};
            ushort_t h[4], lo[4];
            #pragma unroll
            for (int k = 0; k < 4; ++k) {
                h[k]  = f2bf(vv[k]);
                lo[k] = f2bf(vv[k] - bf2f(h[k]));
            }
            *(ushort4*)&ahi[r][j] = make_ushort4(h[0], h[1], h[2], h[3]);
            *(ushort4*)&alo[r][j] = make_ushort4(lo[0], lo[1], lo[2], lo[3]);
        }
        {   // stage V chunk 64t x 128d transposed into vt[d][t]
            int tt = tid & 63, dbase = (tid >> 6) << 5;   // 0,32,64,96
            const ushort_t* vsrc = vsrc0 + (size_t)(tc * 64 + tt) * 128 + dbase;
            union { uint4 q[4]; ushort_t u[32]; } tmp;
            #pragma unroll
            for (int k = 0; k < 4; ++k) tmp.q[k] = ((const uint4*)vsrc)[k];
            #pragma unroll
            for (int j = 0; j < 32; ++j) vt[dbase + j][tt] = tmp.u[j];
        }
        __syncthreads();
        #pragma unroll
        for (int kk = 0; kk < 64; kk += 32) {
            short8 ah = *(const short8*)&ahi[l16][kk + quad * 8];
            short8 al = *(const short8*)&alo[l16][kk + quad * 8];
            #pragma unroll
            for (int n = 0; n < 2; ++n) {
                int d0 = w * 32 + n * 16;
                short8 bf = *(const short8*)&vt[d0 + l16][kk + quad * 8];
                oacc[n] = __builtin_amdgcn_mfma_f32_16x16x32_bf16(ah, bf, oacc[n], 0, 0, 0);
                oacc[n] = __builtin_amdgcn_mfma_f32_16x16x32_bf16(al, bf, oacc[n], 0, 0, 0);
            }
        }
    }

    #pragma unroll
    for (int n = 0; n < 2; ++n) {
        int d0 = w * 32 + n * 16 + l16;
        #pragma unroll
        for (int r = 0; r < 4; ++r)
            obase[(size_t)(quad * 4 + r) * 1024 + d0] = oacc[n][r];
    }
}

// ---------------------------------------------------------------------------
extern "C" void kernel_launch(void* const* d_in, const int* in_sizes, int n_in,
                              void* d_out, int out_size, void* d_ws, size_t ws_size,
                              hipStream_t stream) {
    const float* Q     = (const float*)d_in[0];
    const float* K     = (const float*)d_in[1];
    const float* V     = (const float*)d_in[2];
    const float* route = (const float*)d_in[3];
    const int*   em    = (const int*)d_in[4];
    float* out = (float*)d_out;

    const size_t NB = (size_t)B_ * E_ * S_ * DE_;   // 4.19M elements
    ushort_t* Qb = (ushort_t*)d_ws;
    ushort_t* Kb = Qb + NB;
    ushort_t* Vb = Kb + NB;
    float* attnW = (float*)(Vb + NB);               // [B][S][S] fp32

    prep_kernel<<<4096, 256, 0, stream>>>(Q, K, V, Qb, Kb, Vb);
    dim3 g1(64, 4);
    attn_pass1<<<g1, 256, 0, stream>>>(Qb, Kb, em, attnW);
    dim3 g2(64, 8, 4);
    attn_pass2<<<g2, 256, 0, stream>>>(Vb, attnW, route, out);
}